// Round 2
// baseline (14079.639 us; speedup 1.0000x reference)
//
#include <hip/hip_runtime.h>
#include <hip/hip_fp16.h>

#define RES 512
#define NF 32

static __device__ __forceinline__ float h2f(float v) {
    return __half2float(__float2half(v));
}

// Constant-index component select — folds at compile time under full unroll,
// avoids taking the address of float4 locals (alloca/scratch risk).
#define GET(v, c) ((c) == 0 ? (v).x : ((c) == 1 ? (v).y : ((c) == 2 ? (v).z : (v).w)))

// One thread per point, THREE-PHASE dataflow to cap register pressure ~100
// (previous versions kept >=128 persistent accumulator floats and spilled
// ~6KB/thread to scratch: 13 GB WRITE_SIZE, occupancy 12%).
//   Phase A (gather pass 1): y[32] only.  y[j] = sum_i h16[i]*W1s[i][j],
//     fp16-emulated with numpy-exact op order (identical to passing kernel).
//     h chunks stored to out as they are produced.
//   Phase B (registers only): per-j round/bias/leaky -> o, m_j;
//     g[i] += m_j * W1T[j][i]   (round-0 formulation, fp32, passed).
//   Phase C (gather pass 2): re-interp the per-axis derivative chunks (texels
//     are L2/L3-resident, planes = 100MB < 256MB L3) and fold immediately:
//     n_axis += g[i] * d_axis[i]  (identical fp32 ops/order to round 0).
// Persistent live set per phase: A ~90, B ~70, C ~75 floats ->
// __launch_bounds__(256,4) forces VGPR<=128: no scratch, 2x occupancy.
__global__ __launch_bounds__(256, 4) void stylesdf_fused(
    const float* __restrict__ x,
    const float* __restrict__ planes,
    const float* __restrict__ W1,
    const float* __restrict__ b1,
    const float* __restrict__ W2,
    const float* __restrict__ b2,
    float* __restrict__ out, int N)
{
#pragma clang fp contract(off)
    __shared__ __align__(16) float sW1[NF * NF];   // fp16-valued W1*s, row-major [i][j]
    __shared__ __align__(16) float sW1T[NF * NF];  // transposed [j][i]
    __shared__ __align__(16) float sW2[NF * 4];    // fp16-valued W2*s
    __shared__ __align__(16) float sB1[NF];
    __shared__ __align__(16) float sB2[4];
    __shared__ __align__(16) float sW2c0[NF];

    const float S16 = h2f(0.17677669529663687f);  // fp16(1/sqrt(32))
    const float LREL = h2f(0.2f);                 // fp16(0.2) = 0.199951171875

    const int tid = threadIdx.x;
    for (int idx = tid; idx < NF * NF; idx += 256) {
        float w = h2f(h2f(W1[idx]) * S16);  // fp16 multiply semantics
        sW1[idx] = w;
        sW1T[(idx & 31) * NF + (idx >> 5)] = w;
    }
    if (tid < NF * 4) sW2[tid] = h2f(h2f(W2[tid]) * S16);
    if (tid < NF) { sB1[tid] = h2f(b1[tid]); sW2c0[tid] = h2f(h2f(W2[tid * 4]) * S16); }
    if (tid < 4) sB2[tid] = h2f(b2[tid]);
    __syncthreads();

    const int p = blockIdx.x * 256 + tid;
    if (p >= N) return;

    // ---- per-axis interp coordinates (identical ops to previous kernel) ----
    float fr0, fr1, fr2;
    int a0lo, a0hi, a1lo, a1hi, a2lo, a2hi;
#define AXIS(c, FR, LO, HI)                                 \
    {                                                       \
        float xt = (x[3 * p + (c)] + 1.0f) * 0.5f;          \
        float pos = xt * 511.0f;                            \
        float pf = floorf(pos);                             \
        FR = pos - pf;                                      \
        int q = (int)pf;                                    \
        q = q < 0 ? 0 : (q > 511 ? 511 : q);                \
        LO = q;                                             \
        HI = (q + 1 > 511) ? 511 : q + 1;                   \
    }
    AXIS(0, fr0, a0lo, a0hi)
    AXIS(1, fr1, a1lo, a1hi)
    AXIS(2, fr2, a2lo, a2hi)
#undef AXIS

    // element offsets (floats) of the 12 corner rows; uniform plane bases stay
    // in SGPRs so each load needs only one 32-bit VGPR offset.
    const int oA00 = (a0lo * RES + a1lo) << 5;
    const int oA01 = (a0lo * RES + a1hi) << 5;
    const int oA10 = (a0hi * RES + a1lo) << 5;
    const int oA11 = (a0hi * RES + a1hi) << 5;
    const int oB00 = (a0lo * RES + a2lo) << 5;
    const int oB01 = (a0lo * RES + a2hi) << 5;
    const int oB10 = (a0hi * RES + a2lo) << 5;
    const int oB11 = (a0hi * RES + a2hi) << 5;
    const int oC00 = (a1lo * RES + a2lo) << 5;
    const int oC01 = (a1lo * RES + a2hi) << 5;
    const int oC10 = (a1hi * RES + a2lo) << 5;
    const int oC11 = (a1hi * RES + a2hi) << 5;
    const float* pl0 = planes;
    const float* pl1 = planes + RES * RES * NF;
    const float* pl2 = planes + 2 * (RES * RES * NF);

#define LD4(base, off, q) (*(const float4*)((base) + (off) + 4 * (q)))

    const float ifa01 = 1.0f - fr0, ifb01 = 1.0f - fr1;  // plane0 axes (0,1)
    const float ifa02 = 1.0f - fr0, ifb02 = 1.0f - fr2;  // plane1 axes (0,2)
    const float ifa12 = 1.0f - fr1, ifb12 = 1.0f - fr2;  // plane2 axes (1,2)

    // =================== Phase A: forward y (and h store) ===================
    float y[NF];
#pragma unroll
    for (int j = 0; j < NF; ++j) y[j] = 0.f;

    float4* ho = (float4*)(out + (size_t)N + (size_t)p * NF);

#pragma unroll
    for (int q = 0; q < 8; ++q) {
        float hc[4];
        {  // plane 0, axes (0,1): bitwise h order: h = (h + t4) + t8
            const float4 v00 = LD4(pl0, oA00, q), v01 = LD4(pl0, oA01, q);
            const float4 v10 = LD4(pl0, oA10, q), v11 = LD4(pl0, oA11, q);
#pragma unroll
            for (int c = 0; c < 4; ++c) {
                const float a00 = GET(v00, c), a01 = GET(v01, c);
                const float a10 = GET(v10, c), a11 = GET(v11, c);
                const float t4 = (a00 * ifb01 + a01 * fr1) * ifa01;
                const float t8 = (a10 * ifb01 + a11 * fr1) * fr0;
                hc[c] = t4 + t8;  // h starts at 0: (0+t4)+t8 == t4+t8
            }
        }
        {  // plane 1, axes (0,2)
            const float4 v00 = LD4(pl1, oB00, q), v01 = LD4(pl1, oB01, q);
            const float4 v10 = LD4(pl1, oB10, q), v11 = LD4(pl1, oB11, q);
#pragma unroll
            for (int c = 0; c < 4; ++c) {
                const float a00 = GET(v00, c), a01 = GET(v01, c);
                const float a10 = GET(v10, c), a11 = GET(v11, c);
                const float t4 = (a00 * ifb02 + a01 * fr2) * ifa02;
                const float t8 = (a10 * ifb02 + a11 * fr2) * fr0;
                hc[c] = (hc[c] + t4) + t8;
            }
        }
        {  // plane 2, axes (1,2)
            const float4 v00 = LD4(pl2, oC00, q), v01 = LD4(pl2, oC01, q);
            const float4 v10 = LD4(pl2, oC10, q), v11 = LD4(pl2, oC11, q);
#pragma unroll
            for (int c = 0; c < 4; ++c) {
                const float a00 = GET(v00, c), a01 = GET(v01, c);
                const float a10 = GET(v10, c), a11 = GET(v11, c);
                const float t4 = (a00 * ifb12 + a01 * fr2) * ifa12;
                const float t8 = (a10 * ifb12 + a11 * fr2) * fr1;
                hc[c] = (hc[c] + t4) + t8;
            }
        }

        ho[q] = make_float4(hc[0], hc[1], hc[2], hc[3]);  // fp32 h, np order

        // rank-4 update of y: i ascending, round mul then round add (contract
        // off), identical op sequence to the reference numpy half dot.
#pragma unroll
        for (int c = 0; c < 4; ++c) {
            const float hi = h2f(hc[c]);  // h16
            const float4* row = (const float4*)(sW1 + (4 * q + c) * NF);
#pragma unroll
            for (int jq = 0; jq < 8; ++jq) {
                const float4 w = row[jq];
                y[4 * jq + 0] = y[4 * jq + 0] + hi * w.x;
                y[4 * jq + 1] = y[4 * jq + 1] + hi * w.y;
                y[4 * jq + 2] = y[4 * jq + 2] + hi * w.z;
                y[4 * jq + 3] = y[4 * jq + 3] + hi * w.w;
            }
        }
    }

    // ============ Phase B: activations, layer 2, g = W1s @ m ============
    float o0 = 0.f, o1 = 0.f, o2 = 0.f, o3 = 0.f;
    float g[NF];
#pragma unroll
    for (int i = 0; i < NF; ++i) g[i] = 0.f;
#pragma unroll
    for (int j = 0; j < NF; ++j) {
        const float yd = h2f(y[j]);            // fp16 dot result
        const float y16 = h2f(yd + sB1[j]);    // fp16 bias add
        const bool nn = y16 >= 0.0f;
        const float zj = nn ? y16 : h2f(LREL * y16);  // fp16 leaky value
        const float4 w2 = ((const float4*)sW2)[j];
        o0 = o0 + zj * w2.x;  // sequential fp32 accumulation over j
        o1 = o1 + zj * w2.y;
        o2 = o2 + zj * w2.z;
        o3 = o3 + zj * w2.w;
        const float mj = (nn ? 1.0f : LREL) * sW2c0[j];
        const float4* rowT = (const float4*)(sW1T + j * NF);
#pragma unroll
        for (int iq = 0; iq < 8; ++iq) {
            const float4 w = rowT[iq];
            g[4 * iq + 0] = fmaf(mj, w.x, g[4 * iq + 0]);
            g[4 * iq + 1] = fmaf(mj, w.y, g[4 * iq + 1]);
            g[4 * iq + 2] = fmaf(mj, w.z, g[4 * iq + 2]);
            g[4 * iq + 3] = fmaf(mj, w.w, g[4 * iq + 3]);
        }
    }
    // fp16 rounding of layer-2 output + bias (sdf/rgb pre-activations)
    o0 = h2f(h2f(o0) + sB2[0]);
    o1 = h2f(h2f(o1) + sB2[1]);
    o2 = h2f(h2f(o2) + sB2[2]);
    o3 = h2f(h2f(o3) + sB2[3]);

    // ====== Phase C: re-gather, fold n_axis += g[i] * d_axis[i] ======
    float n0 = 0.f, n1 = 0.f, n2 = 0.f;
#pragma unroll
    for (int q = 0; q < 8; ++q) {
        float d0c[4], d1c[4], d2c[4];
        {  // plane 0
            const float4 v00 = LD4(pl0, oA00, q), v01 = LD4(pl0, oA01, q);
            const float4 v10 = LD4(pl0, oA10, q), v11 = LD4(pl0, oA11, q);
#pragma unroll
            for (int c = 0; c < 4; ++c) {
                const float a00 = GET(v00, c), a01 = GET(v01, c);
                const float a10 = GET(v10, c), a11 = GET(v11, c);
                d0c[c] = (a10 - a00) * ifb01 + (a11 - a01) * fr1;
                d1c[c] = (a01 - a00) * ifa01 + (a11 - a10) * fr0;
            }
        }
        {  // plane 1
            const float4 v00 = LD4(pl1, oB00, q), v01 = LD4(pl1, oB01, q);
            const float4 v10 = LD4(pl1, oB10, q), v11 = LD4(pl1, oB11, q);
#pragma unroll
            for (int c = 0; c < 4; ++c) {
                const float a00 = GET(v00, c), a01 = GET(v01, c);
                const float a10 = GET(v10, c), a11 = GET(v11, c);
                d0c[c] += (a10 - a00) * ifb02 + (a11 - a01) * fr2;
                d2c[c] = (a01 - a00) * ifa02 + (a11 - a10) * fr0;
            }
        }
        {  // plane 2
            const float4 v00 = LD4(pl2, oC00, q), v01 = LD4(pl2, oC01, q);
            const float4 v10 = LD4(pl2, oC10, q), v11 = LD4(pl2, oC11, q);
#pragma unroll
            for (int c = 0; c < 4; ++c) {
                const float a00 = GET(v00, c), a01 = GET(v01, c);
                const float a10 = GET(v10, c), a11 = GET(v11, c);
                d1c[c] += (a10 - a00) * ifb12 + (a11 - a01) * fr2;
                d2c[c] += (a01 - a00) * ifa12 + (a11 - a10) * fr1;
            }
        }
        // n accumulation: i ascending with fmaf — identical to round 0
#pragma unroll
        for (int c = 0; c < 4; ++c) {
            const int i = 4 * q + c;
            n0 = fmaf(g[i], d0c[c], n0);
            n1 = fmaf(g[i], d1c[c], n1);
            n2 = fmaf(g[i], d2c[c], n2);
        }
    }
    n0 *= 511.0f; n1 *= 511.0f; n2 *= 511.0f;

    const float r0 = (tanhf(o1) + 1.0f) * 0.5f;
    const float r1 = (tanhf(o2) + 1.0f) * 0.5f;
    const float r2 = (tanhf(o3) + 1.0f) * 0.5f;

    // ---- stores ----
    out[p] = o0;  // sdf
    {
        const size_t nb = (size_t)N * 33 + (size_t)p * 3;
        out[nb + 0] = n0; out[nb + 1] = n1; out[nb + 2] = n2;
        const size_t rb = (size_t)N * 36 + (size_t)p * 3;
        out[rb + 0] = r0; out[rb + 1] = r1; out[rb + 2] = r2;
    }
#undef LD4
#undef GET
}

extern "C" void kernel_launch(void* const* d_in, const int* in_sizes, int n_in,
                              void* d_out, int out_size, void* d_ws, size_t ws_size,
                              hipStream_t stream) {
    const float* x      = (const float*)d_in[0];
    const float* planes = (const float*)d_in[1];
    const float* W1     = (const float*)d_in[2];
    const float* b1     = (const float*)d_in[3];
    const float* W2     = (const float*)d_in[4];
    const float* b2     = (const float*)d_in[5];
    float* out = (float*)d_out;
    const int N = in_sizes[0] / 3;
    const int blocks = (N + 255) / 256;
    stylesdf_fused<<<blocks, 256, 0, stream>>>(x, planes, W1, b1, W2, b2, out, N);
}

// Round 3
// 893.928 us; speedup vs baseline: 15.7503x; 15.7503x over previous
//
#include <hip/hip_runtime.h>
#include <hip/hip_fp16.h>

#define RES 512
#define NF 32

static __device__ __forceinline__ float h2f(float v) {
    return __half2float(__float2half(v));
}

// Constant-index component select — folds at compile time under full unroll.
#define GET(v, c) ((c) == 0 ? (v).x : ((c) == 1 ? (v).y : ((c) == 2 ? (v).z : (v).w)))

// FOUR LANES PER POINT. Lane q of each group owns features/neurons
// 8q..8q+7. Persistent per-lane state is ~60 floats (h16[8], d0/d1/d2[8],
// y[8], m[8], g[8]) so the kernel CANNOT spill (previous one-point-per-thread
// versions needed >=128 persistent floats -> 13-16 GB scratch WRITE_SIZE).
//
// Exactness: y[j] (whose fp16 value decides every leaky-ReLU sign) is still
// accumulated over ALL i = 0..31 ascending, sequentially, round-mul/round-add
// fp32 with contract off — identical op sequence to the passing kernel; the
// owner lane's h16[i] is broadcast with ds_bpermute. g[i] uses the round-0
// formulation (j ascending, fmaf) with m_j broadcast. Only o (layer-2 fp32
// pre-rounding sums) and n (fp32 nabla dots) are 4-way tree-reduced —
// value-level fp32 reassociation, ~1e-7 relative, far under tolerance.
//
// Gather: the 4 lanes of a point consume each 128B texel row fully
// (fo = 8q + {0,4}) -> perfectly coalesced 128B segments, 8x better cache
// utilization than one-lane-per-point.
__global__ __launch_bounds__(256) void stylesdf_fused(
    const float* __restrict__ x,
    const float* __restrict__ planes,
    const float* __restrict__ W1,
    const float* __restrict__ b1,
    const float* __restrict__ W2,
    const float* __restrict__ b2,
    float* __restrict__ out, int N)
{
#pragma clang fp contract(off)
    __shared__ __align__(16) float sW1[NF * NF];   // fp16-valued W1*s, [i][j]
    __shared__ __align__(16) float sW1T[NF * NF];  // transposed [j][i]
    __shared__ __align__(16) float sW2[NF * 4];    // fp16-valued W2*s
    __shared__ __align__(16) float sB1[NF];
    __shared__ __align__(16) float sB2[4];
    __shared__ __align__(16) float sW2c0[NF];

    const float S16 = h2f(0.17677669529663687f);  // fp16(1/sqrt(32))
    const float LREL = h2f(0.2f);                 // fp16(0.2)

    const int tid = threadIdx.x;
    for (int idx = tid; idx < NF * NF; idx += 256) {
        float w = h2f(h2f(W1[idx]) * S16);  // fp16 multiply semantics
        sW1[idx] = w;
        sW1T[(idx & 31) * NF + (idx >> 5)] = w;
    }
    if (tid < NF * 4) sW2[tid] = h2f(h2f(W2[tid]) * S16);
    if (tid < NF) { sB1[tid] = h2f(b1[tid]); sW2c0[tid] = h2f(h2f(W2[tid * 4]) * S16); }
    if (tid < 4) sB2[tid] = h2f(b2[tid]);
    __syncthreads();

    const int gt = blockIdx.x * 256 + tid;
    const int p = gt >> 2;            // point index
    if (p >= N) return;               // groups of 4 drop together (aligned)
    const int q = gt & 3;             // feature-quarter owned by this lane
    const int f0 = q << 3;            // first feature of this lane's slice
    const int lane4 = (tid & 63) << 2;   // lane byte-index for ds_bpermute
    const int base4 = lane4 & ~15;       // group-of-4 base lane (byte index)

    // ---- per-axis interp coordinates (identical ops to passing kernel) ----
    float fr0, fr1, fr2;
    int a0lo, a0hi, a1lo, a1hi, a2lo, a2hi;
#define AXIS(c, FR, LO, HI)                                 \
    {                                                       \
        float xt = (x[3 * p + (c)] + 1.0f) * 0.5f;          \
        float pos = xt * 511.0f;                            \
        float pf = floorf(pos);                             \
        FR = pos - pf;                                      \
        int qq = (int)pf;                                   \
        qq = qq < 0 ? 0 : (qq > 511 ? 511 : qq);            \
        LO = qq;                                            \
        HI = (qq + 1 > 511) ? 511 : qq + 1;                 \
    }
    AXIS(0, fr0, a0lo, a0hi)
    AXIS(1, fr1, a1lo, a1hi)
    AXIS(2, fr2, a2lo, a2hi)
#undef AXIS

    // element offsets of the 12 corner rows (plane bases stay in SGPRs)
    const int oA00 = (a0lo * RES + a1lo) << 5, oA01 = (a0lo * RES + a1hi) << 5;
    const int oA10 = (a0hi * RES + a1lo) << 5, oA11 = (a0hi * RES + a1hi) << 5;
    const int oB00 = (a0lo * RES + a2lo) << 5, oB01 = (a0lo * RES + a2hi) << 5;
    const int oB10 = (a0hi * RES + a2lo) << 5, oB11 = (a0hi * RES + a2hi) << 5;
    const int oC00 = (a1lo * RES + a2lo) << 5, oC01 = (a1lo * RES + a2hi) << 5;
    const int oC10 = (a1hi * RES + a2lo) << 5, oC11 = (a1hi * RES + a2hi) << 5;
    const float* pl0 = planes;
    const float* pl1 = planes + RES * RES * NF;
    const float* pl2 = planes + 2 * (RES * RES * NF);

#define LD4(b, off) (*(const float4*)((b) + (off)))

    const float ifa01 = 1.0f - fr0, ifb01 = 1.0f - fr1;  // plane0 axes (0,1)
    const float ifa02 = 1.0f - fr0, ifb02 = 1.0f - fr2;  // plane1 axes (0,2)
    const float ifa12 = 1.0f - fr1, ifb12 = 1.0f - fr2;  // plane2 axes (1,2)

    // ============ gather: this lane's 8 features (2 float4 chunks) ============
    float hl[8];                      // fp16-rounded h values (y-matvec input)
    float d0l[8], d1l[8], d2l[8];     // fp32 per-axis derivative values
    float4* ho = (float4*)(out + (size_t)N + (size_t)p * NF);

#pragma unroll
    for (int kk = 0; kk < 2; ++kk) {
        const int fo = f0 + 4 * kk;
        const float4 vA00 = LD4(pl0, oA00 + fo), vA01 = LD4(pl0, oA01 + fo);
        const float4 vA10 = LD4(pl0, oA10 + fo), vA11 = LD4(pl0, oA11 + fo);
        const float4 vB00 = LD4(pl1, oB00 + fo), vB01 = LD4(pl1, oB01 + fo);
        const float4 vB10 = LD4(pl1, oB10 + fo), vB11 = LD4(pl1, oB11 + fo);
        const float4 vC00 = LD4(pl2, oC00 + fo), vC01 = LD4(pl2, oC01 + fo);
        const float4 vC10 = LD4(pl2, oC10 + fo), vC11 = LD4(pl2, oC11 + fo);
        float hc[4];
#pragma unroll
        for (int c = 0; c < 4; ++c) {
            const int f = 4 * kk + c;
            {  // plane 0, axes (0,1): bitwise h order: h = (h + t4) + t8
                const float a00 = GET(vA00, c), a01 = GET(vA01, c);
                const float a10 = GET(vA10, c), a11 = GET(vA11, c);
                const float t4 = (a00 * ifb01 + a01 * fr1) * ifa01;
                const float t8 = (a10 * ifb01 + a11 * fr1) * fr0;
                hc[c] = t4 + t8;  // (0+t4)+t8 == t4+t8 value-exact
                d0l[f] = (a10 - a00) * ifb01 + (a11 - a01) * fr1;
                d1l[f] = (a01 - a00) * ifa01 + (a11 - a10) * fr0;
            }
            {  // plane 1, axes (0,2)
                const float a00 = GET(vB00, c), a01 = GET(vB01, c);
                const float a10 = GET(vB10, c), a11 = GET(vB11, c);
                const float t4 = (a00 * ifb02 + a01 * fr2) * ifa02;
                const float t8 = (a10 * ifb02 + a11 * fr2) * fr0;
                hc[c] = (hc[c] + t4) + t8;
                d0l[f] += (a10 - a00) * ifb02 + (a11 - a01) * fr2;
                d2l[f] = (a01 - a00) * ifa02 + (a11 - a10) * fr0;
            }
            {  // plane 2, axes (1,2)
                const float a00 = GET(vC00, c), a01 = GET(vC01, c);
                const float a10 = GET(vC10, c), a11 = GET(vC11, c);
                const float t4 = (a00 * ifb12 + a01 * fr2) * ifa12;
                const float t8 = (a10 * ifb12 + a11 * fr2) * fr1;
                hc[c] = (hc[c] + t4) + t8;
                d1l[f] += (a10 - a00) * ifb12 + (a11 - a01) * fr2;
                d2l[f] += (a01 - a00) * ifa12 + (a11 - a10) * fr1;
            }
            hl[f] = h2f(hc[c]);  // h16
        }
        // fp32 h store, np order; 4 lanes cover 32 consecutive floats (128B)
        ho[2 * q + kk] = make_float4(hc[0], hc[1], hc[2], hc[3]);
    }

    // ============ y[j] for this lane's 8 j — EXACT i-sequential order ============
    float y[8];
#pragma unroll
    for (int jj = 0; jj < 8; ++jj) y[jj] = 0.f;
#pragma unroll
    for (int i = 0; i < 32; ++i) {
        // broadcast h16[i] from its owner lane (q == i>>3) within the group
        const float hi = __int_as_float(__builtin_amdgcn_ds_bpermute(
            base4 + 4 * (i >> 3), __float_as_int(hl[i & 7])));
        const float4 wA = *(const float4*)(sW1 + i * NF + f0);
        const float4 wB = *(const float4*)(sW1 + i * NF + f0 + 4);
        y[0] = y[0] + hi * wA.x;  // round mul, round add (contract off)
        y[1] = y[1] + hi * wA.y;
        y[2] = y[2] + hi * wA.z;
        y[3] = y[3] + hi * wA.w;
        y[4] = y[4] + hi * wB.x;
        y[5] = y[5] + hi * wB.y;
        y[6] = y[6] + hi * wB.z;
        y[7] = y[7] + hi * wB.w;
    }

    // ============ activations, layer-2 partials, m for this lane's j ============
    float o0 = 0.f, o1 = 0.f, o2 = 0.f, o3 = 0.f;
    float ml[8];
#pragma unroll
    for (int jj = 0; jj < 8; ++jj) {
        const int j = f0 + jj;
        const float yd = h2f(y[jj]);            // fp16 dot result
        const float y16 = h2f(yd + sB1[j]);     // fp16 bias add
        const bool nn = y16 >= 0.0f;
        const float zj = nn ? y16 : h2f(LREL * y16);  // fp16 leaky value
        const float4 w2 = ((const float4*)sW2)[j];
        o0 = o0 + zj * w2.x;  // per-lane partial (reassoc. fp32, pre-round)
        o1 = o1 + zj * w2.y;
        o2 = o2 + zj * w2.z;
        o3 = o3 + zj * w2.w;
        ml[jj] = (nn ? 1.0f : LREL) * sW2c0[j];
    }

    // ============ g[i] for this lane's 8 i — round-0 form, j ascending ============
    float gl[8];
#pragma unroll
    for (int ii = 0; ii < 8; ++ii) gl[ii] = 0.f;
#pragma unroll
    for (int j = 0; j < 32; ++j) {
        const float mj = __int_as_float(__builtin_amdgcn_ds_bpermute(
            base4 + 4 * (j >> 3), __float_as_int(ml[j & 7])));
        const float4 wA = *(const float4*)(sW1T + j * NF + f0);
        const float4 wB = *(const float4*)(sW1T + j * NF + f0 + 4);
        gl[0] = fmaf(mj, wA.x, gl[0]);
        gl[1] = fmaf(mj, wA.y, gl[1]);
        gl[2] = fmaf(mj, wA.z, gl[2]);
        gl[3] = fmaf(mj, wA.w, gl[3]);
        gl[4] = fmaf(mj, wB.x, gl[4]);
        gl[5] = fmaf(mj, wB.y, gl[5]);
        gl[6] = fmaf(mj, wB.z, gl[6]);
        gl[7] = fmaf(mj, wB.w, gl[7]);
    }

    // ============ nabla partials over this lane's i, then 4-way tree add ============
    float n0 = 0.f, n1 = 0.f, n2 = 0.f;
#pragma unroll
    for (int ii = 0; ii < 8; ++ii) {
        n0 = fmaf(gl[ii], d0l[ii], n0);
        n1 = fmaf(gl[ii], d1l[ii], n1);
        n2 = fmaf(gl[ii], d2l[ii], n2);
    }

    // butterfly reduce across the 4 lanes (xor 4, xor 8 in byte-lane space)
#define XADD(v)                                                               \
    v += __int_as_float(__builtin_amdgcn_ds_bpermute(lane4 ^ 4,  __float_as_int(v))); \
    v += __int_as_float(__builtin_amdgcn_ds_bpermute(lane4 ^ 8,  __float_as_int(v)));
    XADD(o0) XADD(o1) XADD(o2) XADD(o3)
    XADD(n0) XADD(n1) XADD(n2)
#undef XADD

    // fp16 rounding of layer-2 output + bias
    o0 = h2f(h2f(o0) + sB2[0]);
    o1 = h2f(h2f(o1) + sB2[1]);
    o2 = h2f(h2f(o2) + sB2[2]);
    o3 = h2f(h2f(o3) + sB2[3]);
    n0 *= 511.0f; n1 *= 511.0f; n2 *= 511.0f;

    // ---- stores: one lane-role each ----
    if (q == 0) out[p] = o0;  // sdf
    if (q == 1) {
        const size_t nb = (size_t)N * 33 + (size_t)p * 3;
        out[nb + 0] = n0; out[nb + 1] = n1; out[nb + 2] = n2;
    }
    if (q == 2) {
        const size_t rb = (size_t)N * 36 + (size_t)p * 3;
        out[rb + 0] = (tanhf(o1) + 1.0f) * 0.5f;
        out[rb + 1] = (tanhf(o2) + 1.0f) * 0.5f;
        out[rb + 2] = (tanhf(o3) + 1.0f) * 0.5f;
    }
#undef LD4
#undef GET
}

extern "C" void kernel_launch(void* const* d_in, const int* in_sizes, int n_in,
                              void* d_out, int out_size, void* d_ws, size_t ws_size,
                              hipStream_t stream) {
    const float* x      = (const float*)d_in[0];
    const float* planes = (const float*)d_in[1];
    const float* W1     = (const float*)d_in[2];
    const float* b1     = (const float*)d_in[3];
    const float* W2     = (const float*)d_in[4];
    const float* b2     = (const float*)d_in[5];
    float* out = (float*)d_out;
    const int N = in_sizes[0] / 3;
    const long long total = 4LL * N;
    const int blocks = (int)((total + 255) / 256);
    stylesdf_fused<<<blocks, 256, 0, stream>>>(x, planes, W1, b1, W2, b2, out, N);
}